// Round 11
// baseline (105.274 us; speedup 1.0000x reference)
//
#include <hip/hip_runtime.h>
#include <hip/hip_bf16.h>

#define B_DIM 16384
#define P_DIM 4096
#define D_DIM 256
#define BK 32
#define NSTEP (D_DIM / BK)   // 8

typedef float f32x4 __attribute__((ext_vector_type(4)));
typedef __bf16 bf16x8 __attribute__((ext_vector_type(8)));

__device__ __forceinline__ unsigned short f2bf_rne(float f) {
  unsigned int u = __builtin_bit_cast(unsigned int, f);
  u += 0x7fffu + ((u >> 16) & 1u);
  return (unsigned short)(u >> 16);
}

// One wave per row: fp32 -> bf16 conversion + fp32 row sum-of-squares.
__global__ __launch_bounds__(256) void prep_kernel(
    const float* __restrict__ x, const float* __restrict__ p,
    unsigned short* __restrict__ xb, unsigned short* __restrict__ pb,
    float* __restrict__ xsq, float* __restrict__ psq) {
  int row  = blockIdx.x * 4 + (threadIdx.x >> 6);
  int lane = threadIdx.x & 63;
  const float4* src;
  unsigned short* dst;
  float* sq;
  if (row < B_DIM) {
    src = (const float4*)(x + (size_t)row * D_DIM);
    dst = xb + (size_t)row * D_DIM;
    sq  = xsq + row;
  } else {
    int r = row - B_DIM;
    src = (const float4*)(p + (size_t)r * D_DIM);
    dst = pb + (size_t)r * D_DIM;
    sq  = psq + r;
  }
  float4 v = src[lane];
  ushort4 o;
  o.x = f2bf_rne(v.x); o.y = f2bf_rne(v.y);
  o.z = f2bf_rne(v.z); o.w = f2bf_rne(v.w);
  ((ushort4*)dst)[lane] = o;
  float s = v.x * v.x + v.y * v.y + v.z * v.z + v.w * v.w;
  #pragma unroll
  for (int off = 32; off > 0; off >>= 1) s += __shfl_down(s, off);
  if (lane == 0) *sq = s;
}

__device__ __forceinline__ void async16(const unsigned short* g, const void* l) {
  __builtin_amdgcn_global_load_lds(
      (const __attribute__((address_space(1))) void*)g,
      (__attribute__((address_space(3))) void*)l,
      16, 0, 0);
}

// R11: wave-autonomous GEMM. 128x128 block = 4 waves, each wave owns a
// 64x64 tile with PRIVATE dbuf LDS (2x8KB). NO s_barrier anywhere in the
// K-loop; only per-wave counted vmcnt(8). 2 blocks/CU -> 8 independent
// wave pipelines per CU; one wave's L2 miss stalls nobody else.
__global__ __launch_bounds__(256, 2) void dist_gemm(
    const unsigned short* __restrict__ A,   // [B_DIM][D_DIM] bf16 bits
    const unsigned short* __restrict__ Bm,  // [P_DIM][D_DIM] bf16 bits
    const float* __restrict__ xsq, const float* __restrict__ psq,
    float* __restrict__ out) {
  __shared__ __align__(16) char lds[4][2][2][4096];  // [wave][buf][A|B][4KB]

  const int tid  = threadIdx.x;
  const int w    = tid >> 6;
  const int lane = tid & 63;
  const int bid  = blockIdx.x;

  // XCD-chunked bijective swizzle (4096 blocks, 8 XCDs).
  const int swz = (bid & 7) * 512 + (bid >> 3);
  const int bm  = swz >> 5;   // 0..127
  const int bn  = swz & 31;   // 0..31

  const int wr = w >> 1;      // 0..1
  const int wc = w & 1;       // 0..1
  const int arowB = bm * 128 + wr * 64;
  const int browB = bn * 128 + wc * 64;

  // ---- wave-private staging geometry ----
  // Instr i (0..3 per matrix): row = i*16 + (lane>>2), LDS byte = i*1024 +
  // lane*16 (lane-linear, rule 21). Chunk swizzle: slot = chunk ^ ((row>>1)&3)
  // -> source chunk for slot (lane&3) is (lane&3) ^ ((srow>>1)&3).
  const int srow   = lane >> 2;                         // 0..15 (+i*16)
  const int schunk = (lane & 3) ^ ((srow >> 1) & 3);    // 16B chunk 0..3
  const unsigned short* aS = A  + (size_t)(arowB + srow) * D_DIM + schunk * 8;
  const unsigned short* bS = Bm + (size_t)(browB + srow) * D_DIM + schunk * 8;

#define STAGE(bufi, ktE) do { _Pragma("unroll")                                \
    for (int i = 0; i < 4; ++i) {                                              \
      async16(aS + (size_t)i * 16 * D_DIM + (ktE),                             \
              (const void*)(&lds[w][bufi][0][i * 1024 + lane * 16]));          \
      async16(bS + (size_t)i * 16 * D_DIM + (ktE),                             \
              (const void*)(&lds[w][bufi][1][i * 1024 + lane * 16]));          \
    } } while (0)

  // ---- fragment read geometry ----
  // A-frag m: row r = m*16 + (lane&15); kslot = lane>>4 (8 k-elems).
  // stored slot = kslot ^ ((r>>1)&3); (r>>1)&3 == ((lane&15)>>1)&3 for all m.
  // Bank check: rows 16 x 16B over 32 banks -> exactly 2-way (free, m136).
  const int rl   = lane & 15;
  const int koff = ((lane >> 4) ^ ((rl >> 1) & 3)) << 4;

  f32x4 acc[4][4];
  #pragma unroll
  for (int m = 0; m < 4; ++m)
    #pragma unroll
    for (int n = 0; n < 4; ++n) acc[m][n] = 0.0f;

  // Prologue: stage k-tile 0 (buf 0). No block barrier anywhere.
  STAGE(0, 0);
  __builtin_amdgcn_sched_barrier(0);

  #pragma unroll
  for (int t = 0; t < NSTEP; ++t) {
    if (t < NSTEP - 1) STAGE((t + 1) & 1, (t + 1) * BK);
    __builtin_amdgcn_sched_barrier(0);
    // Per-wave wait: stage(t) complete; stage(t+1)'s 8 loads in flight.
    if (t < NSTEP - 1) asm volatile("s_waitcnt vmcnt(8)" ::: "memory");
    else               asm volatile("s_waitcnt vmcnt(0)" ::: "memory");
    __builtin_amdgcn_sched_barrier(0);

    const char* La = &lds[w][t & 1][0][0];
    const char* Lb = &lds[w][t & 1][1][0];
    bf16x8 av[4], bv[4];
    #pragma unroll
    for (int m = 0; m < 4; ++m)
      av[m] = *(const bf16x8*)(La + (m * 16 + rl) * 64 + koff);
    #pragma unroll
    for (int n = 0; n < 4; ++n)
      bv[n] = *(const bf16x8*)(Lb + (n * 16 + rl) * 64 + koff);
    // Swapped operands (verified R7/R10): lane holds x-row = m*16+(lane&15),
    // p-cols = n*16 + (lane>>4)*4 + j.
    #pragma unroll
    for (int m = 0; m < 4; ++m)
      #pragma unroll
      for (int n = 0; n < 4; ++n)
        acc[m][n] = __builtin_amdgcn_mfma_f32_16x16x32_bf16(bv[n], av[m], acc[m][n], 0, 0, 0);
    __builtin_amdgcn_sched_barrier(0);
  }

  // ---- Epilogue (identical to R10, per wave) ----
  const int hL = lane >> 4;
  f32x4 ps[4];
  #pragma unroll
  for (int n = 0; n < 4; ++n)
    ps[n] = *(const f32x4*)(psq + browB + n * 16 + hL * 4);

  #pragma unroll
  for (int m = 0; m < 4; ++m) {
    const float xs = xsq[arowB + m * 16 + rl];
    float* orow = out + (size_t)(arowB + m * 16 + rl) * P_DIM + browB + hL * 4;
    #pragma unroll
    for (int n = 0; n < 4; ++n) {
      f32x4 v;
      #pragma unroll
      for (int j = 0; j < 4; ++j) {
        float d = fmaf(-2.0f, acc[m][n][j], xs + ps[n][j]);
        v[j] = __builtin_sqrtf(fmaxf(d, 0.0f));
      }
      *(f32x4*)(orow + n * 16) = v;
    }
  }
#undef STAGE
}

extern "C" void kernel_launch(void* const* d_in, const int* in_sizes, int n_in,
                              void* d_out, int out_size, void* d_ws, size_t ws_size,
                              hipStream_t stream) {
  const float* x = (const float*)d_in[0];
  const float* p = (const float*)d_in[1];
  float* out = (float*)d_out;

  char* ws = (char*)d_ws;
  unsigned short* xb = (unsigned short*)ws;                                // 8 MB
  unsigned short* pb = (unsigned short*)(ws + (size_t)B_DIM * D_DIM * 2);  // 2 MB
  float* xsq = (float*)(ws + (size_t)(B_DIM + P_DIM) * D_DIM * 2);
  float* psq = xsq + B_DIM;

  prep_kernel<<<(B_DIM + P_DIM) / 4, 256, 0, stream>>>(x, p, xb, pb, xsq, psq);

  dist_gemm<<<(B_DIM / 128) * (P_DIM / 128), 256, 0, stream>>>(xb, pb, xsq, psq, out);
}